// Round 2
// baseline (10416.827 us; speedup 1.0000x reference)
//
#include <hip/hip_runtime.h>
#include <hip/hip_bf16.h>

// Problem: B=2, S=2048, D=1024, H=16, DH=64. f32 in/out (per reference).
#define Bn 2
#define Sn 2048
#define Dn 1024
#define Hn 16
#define DHn 64
#define Mn (Bn * Sn)          // 4096 rows
#define LN10K 9.210340371976184f

// ---------------------------------------------------------------------------
// Fused GEMM: out = A(M x 1024) @ W(1024 x N) + bias.
// MODE 0: N=2048, epilogue applies RoPE and scatters to Q (o0) / K (o1),
//         layout (b,h,s,dh) f32.
// MODE 1: N=1024, epilogue scatters to V (o0), layout (b,h,s,dh) f32.
// Tiling: 64x64 block tile, 256 threads, 4x4 per-thread micro-tile, KT=16.
// ---------------------------------------------------------------------------
template <int MODE>
__global__ __launch_bounds__(256) void gemm_fused(
    const float* __restrict__ A, const float* __restrict__ W,
    const float* __restrict__ bias, float* __restrict__ o0,
    float* __restrict__ o1, int N)
{
    __shared__ float At[16][64];   // [kk][row]  (A tile transposed)
    __shared__ float Bt[16][64];   // [kk][col]

    const int K = 1024;
    const int tid = threadIdx.x;
    const int tx = tid & 15, ty = tid >> 4;
    const int rbase = blockIdx.y * 64;
    const int cbase = blockIdx.x * 64;

    float acc[4][4] = {};

    const int arow = tid >> 2;           // 0..63
    const int ak0  = (tid & 3) * 4;      // 0,4,8,12
    const int bkk  = tid >> 4;           // 0..15
    const int bc0  = (tid & 15) * 4;     // 0..60

    const float* Aptr = A + (size_t)(rbase + arow) * K + ak0;
    const float* Wptr = W + (size_t)bkk * N + cbase + bc0;

    for (int kb = 0; kb < K; kb += 16) {
        float4 av = *(const float4*)(Aptr + kb);
        float4 wv = *(const float4*)(Wptr + (size_t)kb * N);
        At[ak0 + 0][arow] = av.x;
        At[ak0 + 1][arow] = av.y;
        At[ak0 + 2][arow] = av.z;
        At[ak0 + 3][arow] = av.w;
        *(float4*)&Bt[bkk][bc0] = wv;
        __syncthreads();
#pragma unroll
        for (int kk = 0; kk < 16; ++kk) {
            float4 a = *(float4*)&At[kk][ty * 4];
            float4 b = *(float4*)&Bt[kk][tx * 4];
            acc[0][0] += a.x * b.x; acc[0][1] += a.x * b.y;
            acc[0][2] += a.x * b.z; acc[0][3] += a.x * b.w;
            acc[1][0] += a.y * b.x; acc[1][1] += a.y * b.y;
            acc[1][2] += a.y * b.z; acc[1][3] += a.y * b.w;
            acc[2][0] += a.z * b.x; acc[2][1] += a.z * b.y;
            acc[2][2] += a.z * b.z; acc[2][3] += a.z * b.w;
            acc[3][0] += a.w * b.x; acc[3][1] += a.w * b.y;
            acc[3][2] += a.w * b.z; acc[3][3] += a.w * b.w;
        }
        __syncthreads();
    }

#pragma unroll
    for (int i = 0; i < 4; ++i) {
        const int r = rbase + ty * 4 + i;
        const int b = r >> 11;           // r / S
        const int s = r & 2047;          // r % S
#pragma unroll
        for (int jp = 0; jp < 2; ++jp) {
            const int c = cbase + tx * 4 + jp * 2;
            float e = acc[i][jp * 2 + 0] + bias[c];
            float o = acc[i][jp * 2 + 1] + bias[c + 1];
            if (MODE == 0) {
                // RoPE (rotate-every-two, per-element freq index d&31):
                //   out[2i]   = x[2i]*cos(a_{2i})   - x[2i+1]*sin(a_{2i})
                //   out[2i+1] = x[2i+1]*cos(a_{2i+1}) + x[2i]*sin(a_{2i+1})
                const int dh = c & 63;
                const int fe = dh & 31;  // dh even -> fe even, fe+1 = (dh+1)&31
                const float f0 = expf(-LN10K * (float)fe / 32.0f);
                const float f1 = expf(-LN10K * (float)(fe + 1) / 32.0f);
                const float a0 = (float)s * f0;
                const float a1 = (float)s * f1;
                const float re = e * cosf(a0) - o * sinf(a0);
                const float ro = o * cosf(a1) + e * sinf(a1);
                const int h = (c >> 6) & 15;
                float* dst = (c >> 10) ? o1 : o0;
                const int idx = (((b * Hn + h) * Sn) + s) * DHn + dh;
                dst[idx] = re;
                dst[idx + 1] = ro;
            } else {
                const int h = c >> 6;
                const int dh = c & 63;
                const int idx = (((b * Hn + h) * Sn) + s) * DHn + dh;
                o0[idx] = e;
                o0[idx + 1] = o;
            }
        }
    }
}

// ---------------------------------------------------------------------------
// Flash attention: 4 waves/block, each wave owns 4 consecutive q-rows of one
// (b,h). Lane l scores k-row (kb+l); online softmax via wave shuffles; lane l
// accumulates output dim l. Aw layout: (b, s, D) f32.
// ---------------------------------------------------------------------------
__global__ __launch_bounds__(256) void attn_kernel(
    const float* __restrict__ Qw, const float* __restrict__ Kw,
    const float* __restrict__ Vw, float* __restrict__ Aw)
{
    __shared__ float qlds[16][64];
    const int tid = threadIdx.x;
    const int lane = tid & 63, wave = tid >> 6;
    const int row0 = blockIdx.x * 16;        // global q-row base (bh*S + s)

    {
        const int rr = tid >> 4;             // 0..15
        const int d0 = (tid & 15) * 4;
        *(float4*)&qlds[rr][d0] =
            *(const float4*)&Qw[(size_t)(row0 + rr) * DHn + d0];
    }
    __syncthreads();

    const int bh = row0 >> 11;               // same for whole block (16 | 2048)
    const float* Kb = Kw + (size_t)bh * (Sn * DHn);
    const float* Vb = Vw + (size_t)bh * (Sn * DHn);
    const int qr = wave * 4;

    float m0 = -1e30f, m1 = -1e30f, m2 = -1e30f, m3 = -1e30f;
    float l0 = 0.f, l1 = 0.f, l2 = 0.f, l3 = 0.f;
    float o0 = 0.f, o1 = 0.f, o2 = 0.f, o3 = 0.f;

    for (int kb = 0; kb < Sn; kb += 64) {
        const float* kr = Kb + (size_t)(kb + lane) * DHn;
        float s0 = 0.f, s1 = 0.f, s2 = 0.f, s3 = 0.f;
#pragma unroll
        for (int d = 0; d < 64; d += 4) {
            float4 kv = *(const float4*)(kr + d);
            float4 qa = *(const float4*)&qlds[qr + 0][d];
            float4 qb = *(const float4*)&qlds[qr + 1][d];
            float4 qc = *(const float4*)&qlds[qr + 2][d];
            float4 qd = *(const float4*)&qlds[qr + 3][d];
            s0 += kv.x * qa.x + kv.y * qa.y + kv.z * qa.z + kv.w * qa.w;
            s1 += kv.x * qb.x + kv.y * qb.y + kv.z * qb.z + kv.w * qb.w;
            s2 += kv.x * qc.x + kv.y * qc.y + kv.z * qc.z + kv.w * qc.w;
            s3 += kv.x * qd.x + kv.y * qd.y + kv.z * qd.z + kv.w * qd.w;
        }
        s0 *= 0.125f; s1 *= 0.125f; s2 *= 0.125f; s3 *= 0.125f;

        float p0, p1, p2, p3;
#define ROW_UPDATE(sv, mv, lv, ov, pv)                                   \
        {                                                                \
            float cm = sv;                                               \
            for (int off = 32; off; off >>= 1)                           \
                cm = fmaxf(cm, __shfl_xor(cm, off));                     \
            float mn = fmaxf(mv, cm);                                    \
            float al = __expf(mv - mn);                                  \
            pv = __expf(sv - mn);                                        \
            float ps = pv;                                               \
            for (int off = 32; off; off >>= 1) ps += __shfl_xor(ps, off);\
            lv = lv * al + ps;                                           \
            ov *= al;                                                    \
            mv = mn;                                                     \
        }
        ROW_UPDATE(s0, m0, l0, o0, p0)
        ROW_UPDATE(s1, m1, l1, o1, p1)
        ROW_UPDATE(s2, m2, l2, o2, p2)
        ROW_UPDATE(s3, m3, l3, o3, p3)
#undef ROW_UPDATE

#pragma unroll 8
        for (int j = 0; j < 64; ++j) {
            const float v = Vb[(size_t)(kb + j) * DHn + lane];
            o0 += __shfl(p0, j) * v;
            o1 += __shfl(p1, j) * v;
            o2 += __shfl(p2, j) * v;
            o3 += __shfl(p3, j) * v;
        }
    }

    const int b = bh >> 4;
    const int h = bh & 15;
    float oo[4] = {o0 / l0, o1 / l1, o2 / l2, o3 / l3};
#pragma unroll
    for (int i = 0; i < 4; ++i) {
        const int g = row0 + qr + i;
        const int qs = g & 2047;
        Aw[((size_t)b * Sn + qs) * Dn + h * DHn + lane] = oo[i];
    }
}

// ---------------------------------------------------------------------------
// LayerNorm over D=1024 per (b,s) row; f32 output.
// ---------------------------------------------------------------------------
__global__ __launch_bounds__(256) void ln_kernel(
    const float* __restrict__ Aw, const float* __restrict__ gamma,
    const float* __restrict__ beta, float* __restrict__ out)
{
    const int row = blockIdx.x;
    const int tid = threadIdx.x;
    const int d0 = tid * 4;
    const float4 x = *(const float4*)&Aw[(size_t)row * Dn + d0];
    float sum = x.x + x.y + x.z + x.w;
    float sq = x.x * x.x + x.y * x.y + x.z * x.z + x.w * x.w;
    for (int off = 32; off; off >>= 1) {
        sum += __shfl_xor(sum, off);
        sq += __shfl_xor(sq, off);
    }
    __shared__ float red[8];
    const int lane = tid & 63, wave = tid >> 6;
    if (lane == 0) { red[wave] = sum; red[wave + 4] = sq; }
    __syncthreads();
    if (tid == 0) {
        red[0] = red[0] + red[1] + red[2] + red[3];
        red[4] = red[4] + red[5] + red[6] + red[7];
    }
    __syncthreads();
    sum = red[0]; sq = red[4];
    const float mu = sum * (1.0f / Dn);
    const float var = sq * (1.0f / Dn) - mu * mu;
    const float rs = rsqrtf(var + 1e-5f);

    const float4 gv = *(const float4*)&gamma[d0];
    const float4 bv = *(const float4*)&beta[d0];
    float4 ov;
    ov.x = (x.x - mu) * rs * gv.x + bv.x;
    ov.y = (x.y - mu) * rs * gv.y + bv.y;
    ov.z = (x.z - mu) * rs * gv.z + bv.z;
    ov.w = (x.w - mu) * rs * gv.w + bv.w;
    *(float4*)&out[(size_t)row * Dn + d0] = ov;
}

extern "C" void kernel_launch(void* const* d_in, const int* in_sizes, int n_in,
                              void* d_out, int out_size, void* d_ws, size_t ws_size,
                              hipStream_t stream)
{
    const float* x_qk = (const float*)d_in[0];
    const float* x_v  = (const float*)d_in[1];
    const float* W_qk = (const float*)d_in[2];
    const float* b_qk = (const float*)d_in[3];
    const float* W_v  = (const float*)d_in[4];
    const float* b_v  = (const float*)d_in[5];
    const float* g    = (const float*)d_in[6];
    const float* be   = (const float*)d_in[7];

    float* ws = (float*)d_ws;
    float* Qw = ws;                       // 4,194,304 f32 (16 MB)
    float* Kw = ws + 4194304;             // 16 MB
    float* Vw = ws + 8388608;             // 16 MB
    float* Aw = ws + 12582912;            // 16 MB

    // GEMM1: x_qk @ W_qk + b_qk, RoPE epilogue -> Q, K
    gemm_fused<0><<<dim3(2048 / 64, Mn / 64), 256, 0, stream>>>(
        x_qk, W_qk, b_qk, Qw, Kw, 2048);
    // GEMM2: x_v @ W_v + b_v -> V
    gemm_fused<1><<<dim3(1024 / 64, Mn / 64), 256, 0, stream>>>(
        x_v, W_v, b_v, Vw, nullptr, 1024);
    // Flash attention -> Aw (b, s, D)
    attn_kernel<<<(Bn * Hn * Sn) / 16, 256, 0, stream>>>(Qw, Kw, Vw, Aw);
    // LayerNorm -> f32 out
    ln_kernel<<<Bn * Sn, 256, 0, stream>>>(Aw, g, be, (float*)d_out);
}

// Round 3
// 604.761 us; speedup vs baseline: 17.2247x; 17.2247x over previous
//
#include <hip/hip_runtime.h>
#include <hip/hip_bf16.h>

// B=2, S=2048, D=1024, H=16, DH=64. f32 in/out; bf16 intermediates for MFMA.
#define Bn 2
#define Sn 2048
#define Dn 1024
#define Hn 16
#define DHn 64
#define Mn (Bn * Sn)
#define LN10K 9.210340371976184f

typedef __attribute__((ext_vector_type(8))) short bf16x8;  // MFMA A/B frag (4 VGPR)
typedef __attribute__((ext_vector_type(4))) float f32x4;   // MFMA C/D frag

static __device__ __forceinline__ ushort f2bf(float f) {
    uint u = __float_as_uint(f);
    u += 0x7fff + ((u >> 16) & 1);   // round-nearest-even
    return (ushort)(u >> 16);
}

#define MFMA16(a, b, c) __builtin_amdgcn_mfma_f32_16x16x32_bf16((a), (b), (c), 0, 0, 0)

// ---------------------------------------------------------------------------
// Fused GEMM (f32 compute, bf16 outputs for the attention stage):
// MODE 0: N=2048. epilogue: +bias, RoPE, Q scaled by 0.125 (folded score
//         scale), writes Q (o0) and K (o1) bf16 in (b,h,s,dh).
// MODE 1: N=1024. epilogue: +bias, writes V TRANSPOSED bf16 (b,h,dh,s) so the
//         attention PV B-fragment is a contiguous 16B load along s.
// ---------------------------------------------------------------------------
template <int MODE>
__global__ __launch_bounds__(256) void gemm_fused(
    const float* __restrict__ A, const float* __restrict__ W,
    const float* __restrict__ bias, ushort* __restrict__ o0,
    ushort* __restrict__ o1, int N)
{
    __shared__ float At[16][64];   // [kk][row]
    __shared__ float Bt[16][64];   // [kk][col]

    const int K = 1024;
    const int tid = threadIdx.x;
    const int tx = tid & 15, ty = tid >> 4;
    const int rbase = blockIdx.y * 64;
    const int cbase = blockIdx.x * 64;

    float acc[4][4] = {};

    const int arow = tid >> 2;
    const int ak0  = (tid & 3) * 4;
    const int bkk  = tid >> 4;
    const int bc0  = (tid & 15) * 4;

    const float* Aptr = A + (size_t)(rbase + arow) * K + ak0;
    const float* Wptr = W + (size_t)bkk * N + cbase + bc0;

    for (int kb = 0; kb < K; kb += 16) {
        float4 av = *(const float4*)(Aptr + kb);
        float4 wv = *(const float4*)(Wptr + (size_t)kb * N);
        At[ak0 + 0][arow] = av.x;
        At[ak0 + 1][arow] = av.y;
        At[ak0 + 2][arow] = av.z;
        At[ak0 + 3][arow] = av.w;
        *(float4*)&Bt[bkk][bc0] = wv;
        __syncthreads();
#pragma unroll
        for (int kk = 0; kk < 16; ++kk) {
            float4 a = *(float4*)&At[kk][ty * 4];
            float4 b = *(float4*)&Bt[kk][tx * 4];
            acc[0][0] += a.x * b.x; acc[0][1] += a.x * b.y;
            acc[0][2] += a.x * b.z; acc[0][3] += a.x * b.w;
            acc[1][0] += a.y * b.x; acc[1][1] += a.y * b.y;
            acc[1][2] += a.y * b.z; acc[1][3] += a.y * b.w;
            acc[2][0] += a.z * b.x; acc[2][1] += a.z * b.y;
            acc[2][2] += a.z * b.z; acc[2][3] += a.z * b.w;
            acc[3][0] += a.w * b.x; acc[3][1] += a.w * b.y;
            acc[3][2] += a.w * b.z; acc[3][3] += a.w * b.w;
        }
        __syncthreads();
    }

#pragma unroll
    for (int i = 0; i < 4; ++i) {
        const int r = rbase + ty * 4 + i;
        const int b = r >> 11;
        const int s = r & 2047;
#pragma unroll
        for (int jp = 0; jp < 2; ++jp) {
            const int c = cbase + tx * 4 + jp * 2;
            float e = acc[i][jp * 2 + 0] + bias[c];
            float o = acc[i][jp * 2 + 1] + bias[c + 1];
            if (MODE == 0) {
                const int dh = c & 63;
                const int fe = dh & 31;
                const float f0 = expf(-LN10K * (float)fe / 32.0f);
                const float f1 = expf(-LN10K * (float)(fe + 1) / 32.0f);
                const float a0 = (float)s * f0;
                const float a1 = (float)s * f1;
                float re = e * cosf(a0) - o * sinf(a0);
                float ro = o * cosf(a1) + e * sinf(a1);
                const int h = (c >> 6) & 15;
                ushort* dst = (c >> 10) ? o1 : o0;
                const float sc = (c >> 10) ? 1.0f : 0.125f;  // fold 1/sqrt(64) into Q
                const size_t idx = (((size_t)(b * Hn + h) * Sn) + s) * DHn + dh;
                dst[idx] = f2bf(re * sc);
                dst[idx + 1] = f2bf(ro * sc);
            } else {
                const int h = c >> 6;
                const int dh = c & 63;
                // V^T: (b, h, dh, s)
                const size_t idx = (((size_t)(b * Hn + h) * DHn) + dh) * Sn + s;
                o0[idx] = f2bf(e);
                o0[idx + Sn] = f2bf(o);
            }
        }
    }
}

// ---------------------------------------------------------------------------
// MFMA flash attention. 4 independent waves/block, each owns 16 q-rows of one
// (b,h). KV tile = 32 rows. No barriers in the KV loop.
//   QK^T: A = Q frag (row=lane&15 -> q, k=d=(lane>>4)*8+j), B = K frag
//         (col=lane&15 -> k-row, k=d), both contiguous 16B global loads.
//   C layout (verified): col=lane&15, row=(lane>>4)*4+reg.
//   softmax: 16-lane-group shfl reduces; online m/l per q-row (4 regs/lane).
//   P: staged via 1KB/wave LDS buffer Pw[16 q][32 k] to reach the PV A-frag
//      layout; read back as one ds_read_b128 per lane.
//   PV: B = V^T frag -> contiguous 16B load along s from Vt (b,h,dh,s).
// ---------------------------------------------------------------------------
__global__ __launch_bounds__(256) void attn_mfma(
    const ushort* __restrict__ Qg, const ushort* __restrict__ Kg,
    const ushort* __restrict__ Vt, float* __restrict__ Aw)
{
    __shared__ ushort Pw[4][16][32];   // per-wave P tile (q-major)

    const int tid = threadIdx.x;
    const int lane = tid & 63, w = tid >> 6;
    const int g = lane >> 4, c = lane & 15;
    const int bh = blockIdx.y;
    const int b = bh >> 4, h = bh & 15;
    const int q0 = blockIdx.x * 64 + w * 16;

    // Q fragments (persist across KV loop)
    const size_t qrow = ((size_t)bh * Sn + q0 + c) * DHn;
    const bf16x8 qa0 = *(const bf16x8*)&Qg[qrow + g * 8];
    const bf16x8 qa1 = *(const bf16x8*)&Qg[qrow + 32 + g * 8];

    const ushort* Kb = Kg + (size_t)bh * Sn * DHn;
    const ushort* Vb = Vt + (size_t)bh * DHn * Sn;

    f32x4 acc0 = {0.f, 0.f, 0.f, 0.f};
    f32x4 acc1 = acc0, acc2 = acc0, acc3 = acc0;
    float m[4] = {-1e30f, -1e30f, -1e30f, -1e30f};
    float l[4] = {0.f, 0.f, 0.f, 0.f};

    for (int kb = 0; kb < Sn; kb += 32) {
        // ---- K fragments (two 16-col subtiles x two 32-d halves) ----
        const ushort* k0p = &Kb[(size_t)(kb + c) * DHn + g * 8];
        const ushort* k1p = &Kb[(size_t)(kb + 16 + c) * DHn + g * 8];
        const bf16x8 kf00 = *(const bf16x8*)k0p;
        const bf16x8 kf01 = *(const bf16x8*)(k0p + 32);
        const bf16x8 kf10 = *(const bf16x8*)k1p;
        const bf16x8 kf11 = *(const bf16x8*)(k1p + 32);
        // ---- V^T fragments (independent of softmax; issue early) ----
        const bf16x8 vf0 = *(const bf16x8*)&Vb[(size_t)(0 * 16 + c) * Sn + kb + g * 8];
        const bf16x8 vf1 = *(const bf16x8*)&Vb[(size_t)(1 * 16 + c) * Sn + kb + g * 8];
        const bf16x8 vf2 = *(const bf16x8*)&Vb[(size_t)(2 * 16 + c) * Sn + kb + g * 8];
        const bf16x8 vf3 = *(const bf16x8*)&Vb[(size_t)(3 * 16 + c) * Sn + kb + g * 8];

        // ---- QK^T: two 16x16 score tiles ----
        const f32x4 z = {0.f, 0.f, 0.f, 0.f};
        f32x4 C0 = MFMA16(qa0, kf00, z);
        C0 = MFMA16(qa1, kf01, C0);
        f32x4 C1 = MFMA16(qa0, kf10, z);
        C1 = MFMA16(qa1, kf11, C1);

        // ---- online softmax (per q-row r; k spread over 16 lanes x 2 tiles)
        float al[4];
#pragma unroll
        for (int r = 0; r < 4; ++r) {
            float v = fmaxf(C0[r], C1[r]);
            v = fmaxf(v, __shfl_xor(v, 1));
            v = fmaxf(v, __shfl_xor(v, 2));
            v = fmaxf(v, __shfl_xor(v, 4));
            v = fmaxf(v, __shfl_xor(v, 8));
            const float mn = fmaxf(m[r], v);
            const float a = __expf(m[r] - mn);
            const float e0 = __expf(C0[r] - mn);
            const float e1 = __expf(C1[r] - mn);
            float ps = e0 + e1;
            ps += __shfl_xor(ps, 1);
            ps += __shfl_xor(ps, 2);
            ps += __shfl_xor(ps, 4);
            ps += __shfl_xor(ps, 8);
            l[r] = l[r] * a + ps;
            m[r] = mn;
            al[r] = a;
            Pw[w][g * 4 + r][c] = f2bf(e0);
            Pw[w][g * 4 + r][16 + c] = f2bf(e1);
        }
#pragma unroll
        for (int r = 0; r < 4; ++r) {
            acc0[r] *= al[r];
            acc1[r] *= al[r];
            acc2[r] *= al[r];
            acc3[r] *= al[r];
        }

        // ---- PV: A = P frag (row=c -> q, k=g*8+j), one b128 per lane ----
        const bf16x8 pa = *(const bf16x8*)&Pw[w][c][g * 8];
        acc0 = MFMA16(pa, vf0, acc0);
        acc1 = MFMA16(pa, vf1, acc1);
        acc2 = MFMA16(pa, vf2, acc2);
        acc3 = MFMA16(pa, vf3, acc3);
    }

    // ---- epilogue: divide by l, store f32 to Aw (b, s, D) ----
#pragma unroll
    for (int r = 0; r < 4; ++r) {
        const float inv = 1.0f / l[r];
        const int qs = q0 + g * 4 + r;
        float* dst = &Aw[((size_t)b * Sn + qs) * Dn + h * DHn + c];
        dst[0]  = acc0[r] * inv;
        dst[16] = acc1[r] * inv;
        dst[32] = acc2[r] * inv;
        dst[48] = acc3[r] * inv;
    }
}

// ---------------------------------------------------------------------------
// LayerNorm over D=1024 per (b,s) row; f32 output.
// ---------------------------------------------------------------------------
__global__ __launch_bounds__(256) void ln_kernel(
    const float* __restrict__ Aw, const float* __restrict__ gamma,
    const float* __restrict__ beta, float* __restrict__ out)
{
    const int row = blockIdx.x;
    const int tid = threadIdx.x;
    const int d0 = tid * 4;
    const float4 x = *(const float4*)&Aw[(size_t)row * Dn + d0];
    float sum = x.x + x.y + x.z + x.w;
    float sq = x.x * x.x + x.y * x.y + x.z * x.z + x.w * x.w;
    for (int off = 32; off; off >>= 1) {
        sum += __shfl_xor(sum, off);
        sq += __shfl_xor(sq, off);
    }
    __shared__ float red[8];
    const int lane = tid & 63, wave = tid >> 6;
    if (lane == 0) { red[wave] = sum; red[wave + 4] = sq; }
    __syncthreads();
    if (tid == 0) {
        red[0] = red[0] + red[1] + red[2] + red[3];
        red[4] = red[4] + red[5] + red[6] + red[7];
    }
    __syncthreads();
    sum = red[0]; sq = red[4];
    const float mu = sum * (1.0f / Dn);
    const float var = sq * (1.0f / Dn) - mu * mu;
    const float rs = rsqrtf(var + 1e-5f);

    const float4 gv = *(const float4*)&gamma[d0];
    const float4 bv = *(const float4*)&beta[d0];
    float4 ov;
    ov.x = (x.x - mu) * rs * gv.x + bv.x;
    ov.y = (x.y - mu) * rs * gv.y + bv.y;
    ov.z = (x.z - mu) * rs * gv.z + bv.z;
    ov.w = (x.w - mu) * rs * gv.w + bv.w;
    *(float4*)&out[(size_t)row * Dn + d0] = ov;
}

extern "C" void kernel_launch(void* const* d_in, const int* in_sizes, int n_in,
                              void* d_out, int out_size, void* d_ws, size_t ws_size,
                              hipStream_t stream)
{
    const float* x_qk = (const float*)d_in[0];
    const float* x_v  = (const float*)d_in[1];
    const float* W_qk = (const float*)d_in[2];
    const float* b_qk = (const float*)d_in[3];
    const float* W_v  = (const float*)d_in[4];
    const float* b_v  = (const float*)d_in[5];
    const float* g    = (const float*)d_in[6];
    const float* be   = (const float*)d_in[7];

    // ws layout: Q bf16 (8MB) | K bf16 (8MB) | V^T bf16 (8MB) | Aw f32 (16MB)
    ushort* Qw  = (ushort*)d_ws;
    ushort* Kw  = Qw + 4194304;
    ushort* Vtw = Kw + 4194304;
    float*  Aw  = (float*)((char*)d_ws + (24u << 20));

    gemm_fused<0><<<dim3(2048 / 64, Mn / 64), 256, 0, stream>>>(
        x_qk, W_qk, b_qk, Qw, Kw, 2048);
    gemm_fused<1><<<dim3(1024 / 64, Mn / 64), 256, 0, stream>>>(
        x_v, W_v, b_v, Vtw, nullptr, 1024);
    attn_mfma<<<dim3(Sn / 64, Bn * Hn), 256, 0, stream>>>(Qw, Kw, Vtw, Aw);
    ln_kernel<<<Bn * Sn, 256, 0, stream>>>(Aw, g, be, (float*)d_out);
}

// Round 4
// 363.620 us; speedup vs baseline: 28.6475x; 1.6632x over previous
//
#include <hip/hip_runtime.h>
#include <hip/hip_bf16.h>

// B=2, S=2048, D=1024, H=16, DH=64. f32 in/out; bf16 intermediates for MFMA.
#define Bn 2
#define Sn 2048
#define Dn 1024
#define Hn 16
#define DHn 64
#define Kd 1024
#define Mn (Bn * Sn)
#define LN10K 9.210340371976184f

typedef __attribute__((ext_vector_type(8))) short bf16x8;  // MFMA A/B frag
typedef __attribute__((ext_vector_type(4))) float f32x4;   // MFMA C/D frag

static __device__ __forceinline__ ushort f2bf(float f) {
    uint u = __float_as_uint(f);
    u += 0x7fff + ((u >> 16) & 1);   // round-nearest-even
    return (ushort)(u >> 16);
}

#define MFMA16(a, b, c) __builtin_amdgcn_mfma_f32_16x16x32_bf16((a), (b), (c), 0, 0, 0)

// ---------------------------------------------------------------------------
// RoPE table: ctab/stab[s][fe], s in [0,2048), fe in [0,32). 64K entries each.
// ---------------------------------------------------------------------------
__global__ __launch_bounds__(256) void rope_tab(float* __restrict__ ct,
                                                float* __restrict__ st)
{
    const int idx = blockIdx.x * 256 + threadIdx.x;
    const int s = idx >> 5, fe = idx & 31;
    const float f = expf(-LN10K * (float)fe / 32.0f);
    const float a = (float)s * f;
    ct[idx] = cosf(a);
    st[idx] = sinf(a);
}

// ---------------------------------------------------------------------------
// f32 -> bf16 elementwise (8 per thread).
// ---------------------------------------------------------------------------
__global__ __launch_bounds__(256) void cvt_bf16(const float* __restrict__ in,
                                                ushort* __restrict__ out)
{
    const size_t i = ((size_t)blockIdx.x * 256 + threadIdx.x) * 8;
    const float4 a = *(const float4*)(in + i);
    const float4 b = *(const float4*)(in + i + 4);
    ushort4 lo = make_ushort4(f2bf(a.x), f2bf(a.y), f2bf(a.z), f2bf(a.w));
    ushort4 hi = make_ushort4(f2bf(b.x), f2bf(b.y), f2bf(b.z), f2bf(b.w));
    *(ushort4*)(out + i) = lo;
    *(ushort4*)(out + i + 4) = hi;
}

// ---------------------------------------------------------------------------
// Transpose + convert: in f32 [R][C] -> out bf16 [C][R]. 32x32 tiles.
// ---------------------------------------------------------------------------
__global__ __launch_bounds__(256) void transpose_bf16(
    const float* __restrict__ in, ushort* __restrict__ out, int R, int C)
{
    __shared__ ushort t[32][33];
    const int n0 = blockIdx.x * 32, k0 = blockIdx.y * 32;
    const int x = threadIdx.x, y = threadIdx.y;
#pragma unroll
    for (int i = 0; i < 4; ++i)
        t[y + 8 * i][x] = f2bf(in[(size_t)(k0 + y + 8 * i) * C + n0 + x]);
    __syncthreads();
#pragma unroll
    for (int i = 0; i < 4; ++i)
        out[(size_t)(n0 + y + 8 * i) * R + k0 + x] = t[x][y + 8 * i];
}

// ---------------------------------------------------------------------------
// MFMA GEMM, LDS-free: A [Mn][Kd] bf16, Bt [N][Kd] bf16 (K-major both sides
// -> all fragments are contiguous 16B loads; 4 lanes cover one 64B line).
// 128x128 block tile, 4 waves, each 64x64 = 4x4 MFMA frags, K-step 32.
// MODE 0 (N=2048): epilogue +bias, RoPE via table, Q*0.125 -> Q(o0)/K(o1)
//                  bf16 (b,h,s,dh).
// MODE 1 (N=1024): epilogue +bias -> V^T bf16 (b,h,dh,s) (o0).
// ---------------------------------------------------------------------------
template <int MODE>
__global__ __launch_bounds__(256) void gemm_mfma(
    const ushort* __restrict__ A, const ushort* __restrict__ Bt,
    const float* __restrict__ bias, const float* __restrict__ ctab,
    const float* __restrict__ stab, ushort* __restrict__ o0,
    ushort* __restrict__ o1)
{
    const int tid = threadIdx.x;
    const int lane = tid & 63, w = tid >> 6;
    const int g = lane >> 4, c = lane & 15;
    const int mbase = blockIdx.y * 128 + (w >> 1) * 64;
    const int nbase = blockIdx.x * 128 + (w & 1) * 64;

    f32x4 acc[4][4];
#pragma unroll
    for (int mf = 0; mf < 4; ++mf)
#pragma unroll
        for (int nf = 0; nf < 4; ++nf)
            acc[mf][nf] = (f32x4){0.f, 0.f, 0.f, 0.f};

    const ushort* Ap = A + (size_t)(mbase + c) * Kd + g * 8;
    const ushort* Bp = Bt + (size_t)(nbase + c) * Kd + g * 8;

    for (int k0 = 0; k0 < Kd; k0 += 32) {
        bf16x8 af[4], bfr[4];
#pragma unroll
        for (int mf = 0; mf < 4; ++mf)
            af[mf] = *(const bf16x8*)(Ap + (size_t)mf * 16 * Kd + k0);
#pragma unroll
        for (int nf = 0; nf < 4; ++nf)
            bfr[nf] = *(const bf16x8*)(Bp + (size_t)nf * 16 * Kd + k0);
#pragma unroll
        for (int mf = 0; mf < 4; ++mf)
#pragma unroll
            for (int nf = 0; nf < 4; ++nf)
                acc[mf][nf] = MFMA16(af[mf], bfr[nf], acc[mf][nf]);
    }

#pragma unroll
    for (int nf = 0; nf < 4; ++nf) {
        const int col = nbase + nf * 16 + c;
        const float bs = bias[col];
        if (MODE == 0) {
            const int dh = col & 63, h = (col >> 6) & 15, isK = col >> 10;
            ushort* dst = isK ? o1 : o0;
            const float sc = isK ? 1.0f : 0.125f;   // fold 1/sqrt(64) into Q
            const float* cr = ctab + (dh & 31);
            const float* sr = stab + (dh & 31);
#pragma unroll
            for (int mf = 0; mf < 4; ++mf) {
#pragma unroll
                for (int r = 0; r < 4; ++r) {
                    const int row = mbase + mf * 16 + g * 4 + r;
                    const int s = row & 2047, b = row >> 11;
                    const float v = acc[mf][nf][r] + bs;
                    const float p = __shfl_xor(v, 1);
                    const float cs = cr[s * 32], sn = sr[s * 32];
                    const float ov = (c & 1) ? v * cs + p * sn
                                             : v * cs - p * sn;
                    dst[(((size_t)(b * Hn + h)) * Sn + s) * DHn + dh] =
                        f2bf(ov * sc);
                }
            }
        } else {
            const int h = col >> 6, dh = col & 63;
#pragma unroll
            for (int mf = 0; mf < 4; ++mf) {
#pragma unroll
                for (int r = 0; r < 4; ++r) {
                    const int row = mbase + mf * 16 + g * 4 + r;
                    const int s = row & 2047, b = row >> 11;
                    const float v = acc[mf][nf][r] + bs;
                    o0[(((size_t)(b * Hn + h)) * DHn + dh) * Sn + s] = f2bf(v);
                }
            }
        }
    }
}

// ---------------------------------------------------------------------------
// MFMA flash attention (as round 3; Pw padded 32->40 to kill 8-way conflict).
// ---------------------------------------------------------------------------
__global__ __launch_bounds__(256) void attn_mfma(
    const ushort* __restrict__ Qg, const ushort* __restrict__ Kg,
    const ushort* __restrict__ Vt, float* __restrict__ Aw)
{
    __shared__ ushort Pw[4][16][40];   // padded: row stride 80B -> 2-way (free)

    const int tid = threadIdx.x;
    const int lane = tid & 63, w = tid >> 6;
    const int g = lane >> 4, c = lane & 15;
    const int bh = blockIdx.y;
    const int b = bh >> 4, h = bh & 15;
    const int q0 = blockIdx.x * 64 + w * 16;

    const size_t qrow = ((size_t)bh * Sn + q0 + c) * DHn;
    const bf16x8 qa0 = *(const bf16x8*)&Qg[qrow + g * 8];
    const bf16x8 qa1 = *(const bf16x8*)&Qg[qrow + 32 + g * 8];

    const ushort* Kb = Kg + (size_t)bh * Sn * DHn;
    const ushort* Vb = Vt + (size_t)bh * DHn * Sn;

    f32x4 acc0 = {0.f, 0.f, 0.f, 0.f};
    f32x4 acc1 = acc0, acc2 = acc0, acc3 = acc0;
    float m[4] = {-1e30f, -1e30f, -1e30f, -1e30f};
    float l[4] = {0.f, 0.f, 0.f, 0.f};

    for (int kb = 0; kb < Sn; kb += 32) {
        const ushort* k0p = &Kb[(size_t)(kb + c) * DHn + g * 8];
        const ushort* k1p = &Kb[(size_t)(kb + 16 + c) * DHn + g * 8];
        const bf16x8 kf00 = *(const bf16x8*)k0p;
        const bf16x8 kf01 = *(const bf16x8*)(k0p + 32);
        const bf16x8 kf10 = *(const bf16x8*)k1p;
        const bf16x8 kf11 = *(const bf16x8*)(k1p + 32);
        const bf16x8 vf0 = *(const bf16x8*)&Vb[(size_t)(0 * 16 + c) * Sn + kb + g * 8];
        const bf16x8 vf1 = *(const bf16x8*)&Vb[(size_t)(1 * 16 + c) * Sn + kb + g * 8];
        const bf16x8 vf2 = *(const bf16x8*)&Vb[(size_t)(2 * 16 + c) * Sn + kb + g * 8];
        const bf16x8 vf3 = *(const bf16x8*)&Vb[(size_t)(3 * 16 + c) * Sn + kb + g * 8];

        const f32x4 z = {0.f, 0.f, 0.f, 0.f};
        f32x4 C0 = MFMA16(qa0, kf00, z);
        C0 = MFMA16(qa1, kf01, C0);
        f32x4 C1 = MFMA16(qa0, kf10, z);
        C1 = MFMA16(qa1, kf11, C1);

        float al[4];
#pragma unroll
        for (int r = 0; r < 4; ++r) {
            float v = fmaxf(C0[r], C1[r]);
            v = fmaxf(v, __shfl_xor(v, 1));
            v = fmaxf(v, __shfl_xor(v, 2));
            v = fmaxf(v, __shfl_xor(v, 4));
            v = fmaxf(v, __shfl_xor(v, 8));
            const float mn = fmaxf(m[r], v);
            const float a = __expf(m[r] - mn);
            const float e0 = __expf(C0[r] - mn);
            const float e1 = __expf(C1[r] - mn);
            float ps = e0 + e1;
            ps += __shfl_xor(ps, 1);
            ps += __shfl_xor(ps, 2);
            ps += __shfl_xor(ps, 4);
            ps += __shfl_xor(ps, 8);
            l[r] = l[r] * a + ps;
            m[r] = mn;
            al[r] = a;
            Pw[w][g * 4 + r][c] = f2bf(e0);
            Pw[w][g * 4 + r][16 + c] = f2bf(e1);
        }
#pragma unroll
        for (int r = 0; r < 4; ++r) {
            acc0[r] *= al[r];
            acc1[r] *= al[r];
            acc2[r] *= al[r];
            acc3[r] *= al[r];
        }

        const bf16x8 pa = *(const bf16x8*)&Pw[w][c][g * 8];
        acc0 = MFMA16(pa, vf0, acc0);
        acc1 = MFMA16(pa, vf1, acc1);
        acc2 = MFMA16(pa, vf2, acc2);
        acc3 = MFMA16(pa, vf3, acc3);
    }

#pragma unroll
    for (int r = 0; r < 4; ++r) {
        const float inv = 1.0f / l[r];
        const int qs = q0 + g * 4 + r;
        float* dst = &Aw[((size_t)b * Sn + qs) * Dn + h * DHn + c];
        dst[0]  = acc0[r] * inv;
        dst[16] = acc1[r] * inv;
        dst[32] = acc2[r] * inv;
        dst[48] = acc3[r] * inv;
    }
}

// ---------------------------------------------------------------------------
// LayerNorm over D=1024 per (b,s) row; f32 output.
// ---------------------------------------------------------------------------
__global__ __launch_bounds__(256) void ln_kernel(
    const float* __restrict__ Aw, const float* __restrict__ gamma,
    const float* __restrict__ beta, float* __restrict__ out)
{
    const int row = blockIdx.x;
    const int tid = threadIdx.x;
    const int d0 = tid * 4;
    const float4 x = *(const float4*)&Aw[(size_t)row * Dn + d0];
    float sum = x.x + x.y + x.z + x.w;
    float sq = x.x * x.x + x.y * x.y + x.z * x.z + x.w * x.w;
    for (int off = 32; off; off >>= 1) {
        sum += __shfl_xor(sum, off);
        sq += __shfl_xor(sq, off);
    }
    __shared__ float red[8];
    const int lane = tid & 63, wave = tid >> 6;
    if (lane == 0) { red[wave] = sum; red[wave + 4] = sq; }
    __syncthreads();
    if (tid == 0) {
        red[0] = red[0] + red[1] + red[2] + red[3];
        red[4] = red[4] + red[5] + red[6] + red[7];
    }
    __syncthreads();
    sum = red[0]; sq = red[4];
    const float mu = sum * (1.0f / Dn);
    const float var = sq * (1.0f / Dn) - mu * mu;
    const float rs = rsqrtf(var + 1e-5f);

    const float4 gv = *(const float4*)&gamma[d0];
    const float4 bv = *(const float4*)&beta[d0];
    float4 ov;
    ov.x = (x.x - mu) * rs * gv.x + bv.x;
    ov.y = (x.y - mu) * rs * gv.y + bv.y;
    ov.z = (x.z - mu) * rs * gv.z + bv.z;
    ov.w = (x.w - mu) * rs * gv.w + bv.w;
    *(float4*)&out[(size_t)row * Dn + d0] = ov;
}

extern "C" void kernel_launch(void* const* d_in, const int* in_sizes, int n_in,
                              void* d_out, int out_size, void* d_ws, size_t ws_size,
                              hipStream_t stream)
{
    const float* x_qk = (const float*)d_in[0];
    const float* x_v  = (const float*)d_in[1];
    const float* W_qk = (const float*)d_in[2];
    const float* b_qk = (const float*)d_in[3];
    const float* W_v  = (const float*)d_in[4];
    const float* b_v  = (const float*)d_in[5];
    const float* g    = (const float*)d_in[6];
    const float* be   = (const float*)d_in[7];

    char* ws = (char*)d_ws;
    ushort* Qw    = (ushort*)(ws);                  //  8 MB bf16 (b,h,s,dh)
    ushort* Kw    = (ushort*)(ws + (8u  << 20));    //  8 MB bf16 (b,h,s,dh)
    ushort* Vtw   = (ushort*)(ws + (16u << 20));    //  8 MB bf16 (b,h,dh,s)
    float*  Aw    = (float*) (ws + (24u << 20));    // 16 MB f32  (b,s,D)
    ushort* xqkB  = (ushort*)(ws + (40u << 20));    //  8 MB bf16 [M][K]
    ushort* xvB   = (ushort*)(ws + (48u << 20));    //  8 MB bf16 [M][K]
    ushort* WqkT  = (ushort*)(ws + (56u << 20));    //  4 MB bf16 [2048][1024]
    ushort* WvT   = (ushort*)(ws + (60u << 20));    //  2 MB bf16 [1024][1024]
    float*  ctab  = (float*) (ws + (62u << 20));    // 256 KB
    float*  stab  = (float*) (ws + (62u << 20) + (256u << 10));

    rope_tab<<<256, 256, 0, stream>>>(ctab, stab);
    cvt_bf16<<<2048, 256, 0, stream>>>(x_qk, xqkB);
    cvt_bf16<<<2048, 256, 0, stream>>>(x_v, xvB);
    transpose_bf16<<<dim3(64, 32), dim3(32, 8), 0, stream>>>(W_qk, WqkT, Kd, 2048);
    transpose_bf16<<<dim3(32, 32), dim3(32, 8), 0, stream>>>(W_v, WvT, Kd, 1024);

    gemm_mfma<0><<<dim3(16, 32), 256, 0, stream>>>(
        xqkB, WqkT, b_qk, ctab, stab, Qw, Kw);
    gemm_mfma<1><<<dim3(8, 32), 256, 0, stream>>>(
        xvB, WvT, b_v, ctab, stab, Vtw, nullptr);

    attn_mfma<<<dim3(Sn / 64, Bn * Hn), 256, 0, stream>>>(Qw, Kw, Vtw, Aw);
    ln_kernel<<<Bn * Sn, 256, 0, stream>>>(Aw, g, be, (float*)d_out);
}